// Round 9
// baseline (1890.630 us; speedup 1.0000x reference)
//
#include <hip/hip_runtime.h>
#include <hip/hip_bf16.h>
#include <stdint.h>

typedef unsigned short u16;
typedef unsigned int   u32;

#define NEG_GAT 0.2f
#define NEG_ACT 0.05f
#define LN_EPS  1e-5f
#define NPARAM  15

__device__ __forceinline__ float bf2f(u32 bits16){
  union { u32 u; float f; } v; v.u = bits16 << 16; return v.f;
}
__device__ __forceinline__ u16 f2bf(float f){
  union { float f; u32 u; } v; v.f = f;
  u32 u = v.u;
  u32 r = (u + 0x7fffu + ((u >> 16) & 1u)) >> 16;
  return (u16)r;
}
__device__ __forceinline__ float lrelu(float x, float s){ return x > 0.f ? x : s * x; }

// width-aware integer accessor: enc=0 -> int32, enc=1 -> int64 (low word)
__device__ __forceinline__ int geti(const int* __restrict__ p, int i, int enc){
  return p[enc ? (2 * i) : i];
}

// ---------------- dtype detection ----------------

struct CvtParams {
  const void* src[NPARAM];
  float*      dst[NPARAM];
  int         n[NPARAM];
};

__global__ void k_detect(const u32* __restrict__ ln_g_raw, const int* __restrict__ ei_raw,
                         int* __restrict__ fflag, int* __restrict__ iflag,
                         int* __restrict__ errflag)
{
  if (threadIdx.x == 0){
    *fflag = (ln_g_raw[0] == 0x3F800000u) ? 0 : 1;
    int zeros = 0;
    for (int j = 0; j < 64; j++) if (ei_raw[2 * j + 1] == 0) zeros++;
    *iflag = (zeros >= 60) ? 1 : 0;
    *errflag = 0;
  }
}

__global__ void k_convert(CvtParams P, const int* __restrict__ flag)
{
  const int pi  = blockIdx.y;
  const int idx = blockIdx.x * 256 + threadIdx.x;
  if (idx >= P.n[pi]) return;
  if (*flag == 0) P.dst[pi][idx] = ((const float*)P.src[pi])[idx];
  else            P.dst[pi][idx] = bf2f(((const u16*)P.src[pi])[idx]);
}

// ---------------- validators ----------------

__global__ void k_check_sorted(const int* __restrict__ batch, const int* __restrict__ iflag,
                               int n, int* __restrict__ errflag)
{
  int i = blockIdx.x * 256 + threadIdx.x;
  if (i < n - 1){
    if (geti(batch, i, *iflag) > geti(batch, i + 1, *iflag)) atomicOr(errflag, 8);
  }
}

__global__ void k_check_x(const int* __restrict__ x, const int* __restrict__ iflag,
                          int n, int V, int* __restrict__ errflag)
{
  int i = blockIdx.x * 256 + threadIdx.x;
  if (i < n){
    int v = geti(x, i, *iflag);
    if ((unsigned)v >= (unsigned)V) atomicOr(errflag, 16);
  }
}

__global__ void k_check_edges(const int* __restrict__ ei, const int* __restrict__ iflag,
                              int E, int n, int* __restrict__ errflag)
{
  int e = blockIdx.x * 256 + threadIdx.x;
  if (e < E){
    int enc = *iflag;
    int s = geti(ei, e, enc);
    int d = geti(ei, E + e, enc);
    if ((unsigned)s >= (unsigned)n || (unsigned)d >= (unsigned)n) atomicOr(errflag, 32);
  }
}

// ---------------- CSR build ----------------

__global__ void k_hist(const int* __restrict__ ei, const int* __restrict__ iflag,
                       int* __restrict__ counts, int E, int n)
{
  int e = blockIdx.x * 256 + threadIdx.x;
  if (e < E){
    int d = geti(ei, E + e, *iflag);
    d = min(max(d, 0), n - 1);
    atomicAdd(&counts[d], 1);
  }
}

__global__ void k_scanA(const int* __restrict__ counts, int* __restrict__ rowptr,
                        int* __restrict__ bsums, int n)
{
  __shared__ int sd[1024];
  int tid = threadIdx.x;
  int gid = blockIdx.x * 1024 + tid;
  int v = (gid < n) ? counts[gid] : 0;
  sd[tid] = v;
  __syncthreads();
  for (int off = 1; off < 1024; off <<= 1){
    int t = 0;
    if (tid >= off) t = sd[tid - off];
    __syncthreads();
    if (tid >= off) sd[tid] += t;
    __syncthreads();
  }
  if (gid < n) rowptr[gid] = sd[tid] - v;
  if (tid == 1023) bsums[blockIdx.x] = sd[1023];
}

__global__ void k_scanB(const int* __restrict__ bsums, int* __restrict__ boffs, int nb)
{
  __shared__ int sd[128];
  int tid = threadIdx.x;
  int v = (tid < nb) ? bsums[tid] : 0;
  sd[tid] = v;
  __syncthreads();
  for (int off = 1; off < 128; off <<= 1){
    int t = 0;
    if (tid >= off) t = sd[tid - off];
    __syncthreads();
    if (tid >= off) sd[tid] += t;
    __syncthreads();
  }
  if (tid < nb) boffs[tid] = sd[tid] - v;
}

__global__ void k_scanC(int* __restrict__ rowptr, const int* __restrict__ boffs,
                        int* __restrict__ cursor, int n, int Etot)
{
  int gid = blockIdx.x * 1024 + threadIdx.x;
  if (gid < n){
    int v = rowptr[gid] + boffs[blockIdx.x];
    rowptr[gid] = v;
    cursor[gid] = v;
  }
  if (gid == 0) rowptr[n] = Etot;
}

__global__ void k_scatter(const int* __restrict__ ei, const int* __restrict__ iflag,
                          int* __restrict__ cursor, int* __restrict__ csr, int E, int n)
{
  int e = blockIdx.x * 256 + threadIdx.x;
  if (e < E){
    int enc = *iflag;
    int s = geti(ei, e, enc);          // src = first half
    int d = geti(ei, E + e, enc);      // dst = second half
    d = min(max(d, 0), n - 1);
    int pos = atomicAdd(&cursor[d], 1);
    csr[pos] = s;
  }
}

// ---------------- CSR invariants ----------------

__global__ void k_check_rows(const int* __restrict__ rowptr, const int* __restrict__ cursor,
                             int n, int* __restrict__ errflag)
{
  int i = blockIdx.x * 256 + threadIdx.x;
  if (i < n){
    if (cursor[i] != rowptr[i + 1]) atomicOr(errflag, 1);
    if (i == 0 && rowptr[0] != 0)   atomicOr(errflag, 4);
  }
}

__global__ void k_check_csr(const int* __restrict__ csr, int E, int n, int* __restrict__ errflag)
{
  int e = blockIdx.x * 256 + threadIdx.x;
  if (e < E && (unsigned)csr[e] >= (unsigned)n) atomicOr(errflag, 2);
}

__global__ void k_stamp_if(const int* __restrict__ errflag, float* __restrict__ out, int nel)
{
  int f = *errflag;
  if (f == 0) return;
  float s = 500.0f + 100.0f * (float)f;
  int i = blockIdx.x * 256 + threadIdx.x;
  if (i < nel) out[i] = s;
}

__global__ void k_stamp(float* __restrict__ out, int nel, float val)
{
  int i = blockIdx.x * 256 + threadIdx.x;
  if (i < nel) out[i] = val;
}

// ---------------- node prep layer 1 ----------------

__global__ void k_node1s(const int* __restrict__ x, const int* __restrict__ iflag,
                         const float* __restrict__ emb,
                         const float* __restrict__ ln_g, const float* __restrict__ ln_b,
                         const float* __restrict__ W1, const float* __restrict__ a_src,
                         const float* __restrict__ a_dst, int V,
                         u16* __restrict__ xw, float* __restrict__ al_s, float* __restrict__ al_d)
{
  __shared__ float se[32];
  __shared__ float stats[2];
  __shared__ float sxw[128];
  const int i = blockIdx.x, t = threadIdx.x;
  if (t < 32){
    int v = geti(x, i, *iflag);
    v = min(max(v, 0), V - 1);
    se[t] = emb[v * 32 + t];
  }
  __syncthreads();
  if (t == 0){
    float s1 = 0.f, s2 = 0.f;
    for (int k = 0; k < 32; k++){ s1 += se[k]; s2 += se[k] * se[k]; }
    float mu = s1 * (1.f / 32.f);
    float var = s2 * (1.f / 32.f) - mu * mu;
    stats[0] = mu; stats[1] = rsqrtf(var + LN_EPS);
  }
  __syncthreads();
  const float mu = stats[0], rs = stats[1];
  float o = 0.f;
  for (int k = 0; k < 32; k++){
    float xe = (se[k] - mu) * rs * ln_g[k] + ln_b[k];
    o += xe * W1[k * 128 + t];
  }
  sxw[t] = o;
  xw[(size_t)i * 128 + t] = f2bf(o);
  __syncthreads();
  if (t < 2){
    float ps = 0.f, pd = 0.f;
    for (int d = 0; d < 64; d++){
      float v = sxw[t * 64 + d];
      ps += v * a_src[t * 64 + d];
      pd += v * a_dst[t * 64 + d];
    }
    al_s[2 * i + t] = ps;
    al_d[2 * i + t] = pd;
  }
}

// ---------------- node prep layer 2 (h1 is f32 in d_out) ----------------

__global__ void k_node2s(const float* __restrict__ h1, const float* __restrict__ W2,
                         const float* __restrict__ a_src, const float* __restrict__ a_dst,
                         u16* __restrict__ xw, float* __restrict__ al_s, float* __restrict__ al_d)
{
  __shared__ float sh[128];
  __shared__ float sxw[128];
  const int i = blockIdx.x, t = threadIdx.x;
  sh[t] = h1[(size_t)i * 128 + t];
  __syncthreads();
  float o = 0.f;
  for (int k = 0; k < 128; k++) o += sh[k] * W2[k * 128 + t];
  sxw[t] = o;
  xw[(size_t)i * 128 + t] = f2bf(o);
  __syncthreads();
  if (t < 2){
    float ps = 0.f, pd = 0.f;
    for (int d = 0; d < 64; d++){
      float v = sxw[t * 64 + d];
      ps += v * a_src[t * 64 + d];
      pd += v * a_dst[t * 64 + d];
    }
    al_s[2 * i + t] = ps;
    al_d[2 * i + t] = pd;
  }
}

// ---------------- GAT (writes f32) ----------------

__global__ void k_gats(const int* __restrict__ rowptr, const int* __restrict__ csr,
                       const float* __restrict__ al_s, const float* __restrict__ al_d,
                       const u16* __restrict__ xw, const float* __restrict__ bias,
                       int apply_act, float* __restrict__ out)
{
  __shared__ float sm[2], ss[2];
  const int i = blockIdx.x, t = threadIdx.x;
  const int r0 = rowptr[i], r1 = rowptr[i + 1];
  const int deg = r1 - r0;                    // + virtual self-loop at k==deg
  if (t < 2){
    const int h = t;
    const float ad = al_d[2 * i + h];
    float m = -3.0e38f;
    for (int k = 0; k <= deg; k++){
      int s = (k < deg) ? csr[r0 + k] : i;
      float a = lrelu(al_s[2 * s + h] + ad, NEG_GAT);
      m = fmaxf(m, a);
    }
    float sum = 0.f;
    for (int k = 0; k <= deg; k++){
      int s = (k < deg) ? csr[r0 + k] : i;
      float a = lrelu(al_s[2 * s + h] + ad, NEG_GAT);
      sum += __expf(a - m);
    }
    sm[h] = m; ss[h] = sum;
  }
  __syncthreads();
  const int h = t >> 6;
  const float m = sm[h], inv = 1.f / ss[h], ad = al_d[2 * i + h];
  float acc = 0.f;
  for (int k = 0; k <= deg; k++){
    int s = (k < deg) ? csr[r0 + k] : i;
    float a = lrelu(al_s[2 * s + h] + ad, NEG_GAT);
    float w = __expf(a - m);
    acc += w * bf2f(xw[(size_t)s * 128 + t]);
  }
  float o = acc * inv + bias[t];
  if (apply_act) o = lrelu(o, NEG_ACT);
  out[(size_t)i * 128 + t] = o;
}

// ---------------- gate scalar per node (h f32) ----------------

__global__ void k_gates(const float* __restrict__ h, const float* __restrict__ gw1,
                        const float* __restrict__ gb1, const float* __restrict__ gw2,
                        const float* __restrict__ gb2, float* __restrict__ gate)
{
  __shared__ float sh[128];
  __shared__ float st[64];
  const int i = blockIdx.x, t = threadIdx.x;
  sh[t] = h[(size_t)i * 128 + t];
  __syncthreads();
  if (t < 64){
    float a = 0.f;
    for (int k = 0; k < 128; k++) a += sh[k] * gw1[k * 64 + t];
    st[t] = lrelu(a + gb1[t], NEG_ACT);
  }
  __syncthreads();
  if (t == 0){
    float q = 0.f;
    for (int j = 0; j < 64; j++) q += st[j] * gw2[j];
    gate[i] = q + gb2[0];
  }
}

// ---------------- per-graph softmax pooling (f32 h, f32 z) ----------------

__global__ void k_graphs(const int* __restrict__ batch, const int* __restrict__ iflag,
                         const float* __restrict__ gate,
                         const float* __restrict__ h, float* __restrict__ zout, int N)
{
  __shared__ float sms[2];
  __shared__ int range[2];
  const int g = blockIdx.x, t = threadIdx.x;
  if (t == 0){
    const int enc = *iflag;
    int lo = 0, hi = N;
    while (lo < hi){ int mid = (lo + hi) >> 1; if (geti(batch, mid, enc) < g) lo = mid + 1; else hi = mid; }
    range[0] = lo;
    hi = N;
    while (lo < hi){ int mid = (lo + hi) >> 1; if (geti(batch, mid, enc) < g + 1) lo = mid + 1; else hi = mid; }
    range[1] = lo;
    float m = -3.0e38f;
    for (int k = range[0]; k < range[1]; k++) m = fmaxf(m, gate[k]);
    float s = 0.f;
    for (int k = range[0]; k < range[1]; k++) s += __expf(gate[k] - m);
    sms[0] = m; sms[1] = s;
  }
  __syncthreads();
  const int st = range[0], en = range[1];
  float z = 0.f;
  if (en > st){
    const float m = sms[0], inv = 1.f / sms[1];
    for (int k = st; k < en; k++)
      z += __expf(gate[k] - m) * inv * h[(size_t)k * 128 + t];
  }
  zout[(size_t)g * 128 + t] = z;
}

// ---------------- launch ----------------

extern "C" void kernel_launch(void* const* d_in, const int* in_sizes, int n_in,
                              void* d_out, int out_size, void* d_ws, size_t ws_size,
                              hipStream_t stream)
{
  const int* x      = (const int*)d_in[0];
  const int* ei     = (const int*)d_in[1];
  const int* batch  = (const int*)d_in[2];

  const int N = in_sizes[0];
  const int E = in_sizes[1] / 2;
  const int V = in_sizes[3] / 32;
  const int G = out_size / 128 - N;

  char* p = (char*)d_ws;
  auto alloc = [&](size_t bytes) -> char* {
    char* r = p; p += (bytes + 255) & ~(size_t)255; return r;
  };
  int*   multi  = (int*)  alloc((size_t)N * 4);       // counts -> cursor -> gate
  int*   rowptr = (int*)  alloc((size_t)(N + 1) * 4);
  int*   csr    = (int*)  alloc((size_t)E * 4);
  int*   bsums  = (int*)  alloc(4096);
  int*   boffs  = (int*)  alloc(4096);
  int*   flags  = (int*)  alloc(256);
  int*   fflag  = flags;
  int*   iflag  = flags + 1;
  int*   errflg = flags + 2;
  float* al_s   = (float*)alloc((size_t)N * 2 * 4);
  float* al_d   = (float*)alloc((size_t)N * 2 * 4);
  u16*   xw     = (u16*)  alloc((size_t)N * 128 * 2);

  CvtParams cp;
  float* fpar[NPARAM];
  int maxn = 0;
  for (int pi = 0; pi < NPARAM; pi++){
    int n = in_sizes[3 + pi];
    fpar[pi] = (float*)alloc((size_t)n * 4);
    cp.src[pi] = d_in[3 + pi];
    cp.dst[pi] = fpar[pi];
    cp.n[pi]   = n;
    if (n > maxn) maxn = n;
  }
  const size_t needed = (size_t)(p - (char*)d_ws);

  const float* emb    = fpar[0];
  const float* ln_g   = fpar[1];
  const float* ln_b   = fpar[2];
  const float* W1     = fpar[3];
  const float* a_src1 = fpar[4];
  const float* a_dst1 = fpar[5];
  const float* b1     = fpar[6];
  const float* W2     = fpar[7];
  const float* a_src2 = fpar[8];
  const float* a_dst2 = fpar[9];
  const float* b2     = fpar[10];
  const float* gw1    = fpar[11];
  const float* gb1    = fpar[12];
  const float* gw2    = fpar[13];
  const float* gb2    = fpar[14];
  (void)n_in;

  int ob = (out_size + 255) / 256;
  if (ws_size < needed){
    k_stamp<<<ob, 256, 0, stream>>>((float*)d_out, out_size, 9999.0f);
    return;
  }

  int*   counts = multi;
  int*   cursor = multi;
  float* gate   = (float*)multi;
  float* hbuf   = (float*)d_out;                       // f32 h region (also h1 between layers)
  float* zbuf   = (float*)d_out + (size_t)N * 128;     // f32 z region

  k_detect<<<1, 64, 0, stream>>>((const u32*)d_in[4], ei, fflag, iflag, errflg);
  dim3 cgrid((maxn + 255) / 256, NPARAM);
  k_convert<<<cgrid, 256, 0, stream>>>(cp, fflag);

  int eb = (E + 255) / 256;
  int nb = (N + 1023) / 1024;
  int nb256 = (N + 255) / 256;

  k_check_sorted<<<nb256, 256, 0, stream>>>(batch, iflag, N, errflg);
  k_check_x<<<nb256, 256, 0, stream>>>(x, iflag, N, V, errflg);
  k_check_edges<<<eb, 256, 0, stream>>>(ei, iflag, E, N, errflg);

  hipMemsetAsync(counts, 0, (size_t)N * 4, stream);
  hipMemsetAsync(csr, 0xFF, (size_t)E * 4, stream);
  k_hist<<<eb, 256, 0, stream>>>(ei, iflag, counts, E, N);
  k_scanA<<<nb, 1024, 0, stream>>>(counts, rowptr, bsums, N);
  k_scanB<<<1, 128, 0, stream>>>(bsums, boffs, nb);
  k_scanC<<<nb, 1024, 0, stream>>>(rowptr, boffs, cursor, N, E);
  k_scatter<<<eb, 256, 0, stream>>>(ei, iflag, cursor, csr, E, N);
  k_check_rows<<<nb256, 256, 0, stream>>>(rowptr, cursor, N, errflg);
  k_check_csr<<<eb, 256, 0, stream>>>(csr, E, N, errflg);

  k_node1s<<<N, 128, 0, stream>>>(x, iflag, emb, ln_g, ln_b, W1, a_src1, a_dst1, V, xw, al_s, al_d);
  k_gats<<<N, 128, 0, stream>>>(rowptr, csr, al_s, al_d, xw, b1, 1, hbuf);
  k_node2s<<<N, 128, 0, stream>>>(hbuf, W2, a_src2, a_dst2, xw, al_s, al_d);
  k_gats<<<N, 128, 0, stream>>>(rowptr, csr, al_s, al_d, xw, b2, 0, hbuf);

  k_gates<<<N, 128, 0, stream>>>(hbuf, gw1, gb1, gw2, gb2, gate);
  k_graphs<<<G, 128, 0, stream>>>(batch, iflag, gate, hbuf, zbuf, N);

  k_stamp_if<<<ob, 256, 0, stream>>>(errflg, (float*)d_out, out_size);
}

// Round 10
// 894.107 us; speedup vs baseline: 2.1145x; 2.1145x over previous
//
#include <hip/hip_runtime.h>
#include <hip/hip_bf16.h>
#include <stdint.h>

typedef unsigned short u16;
typedef unsigned int   u32;

#define NEG_GAT 0.2f
#define NEG_ACT 0.05f
#define LN_EPS  1e-5f
#define NPARAM  15

__device__ __forceinline__ float bf2f(u32 bits16){
  union { u32 u; float f; } v; v.u = bits16 << 16; return v.f;
}
__device__ __forceinline__ u16 f2bf(float f){
  union { float f; u32 u; } v; v.f = f;
  u32 u = v.u;
  u32 r = (u + 0x7fffu + ((u >> 16) & 1u)) >> 16;
  return (u16)r;
}
__device__ __forceinline__ float lrelu(float x, float s){ return x > 0.f ? x : s * x; }

// width-aware integer accessor: enc=0 -> int32, enc=1 -> int64 (low word)
__device__ __forceinline__ int geti(const int* __restrict__ p, int i, int enc){
  return p[enc ? (2 * i) : i];
}

// ---------------- dtype detection ----------------

struct CvtParams {
  const void* src[NPARAM];
  float*      dst[NPARAM];
  int         n[NPARAM];
};

__global__ void k_detect(const u32* __restrict__ ln_g_raw, const int* __restrict__ ei_raw,
                         int* __restrict__ fflag, int* __restrict__ iflag,
                         int* __restrict__ errflag)
{
  if (threadIdx.x == 0){
    *fflag = (ln_g_raw[0] == 0x3F800000u) ? 0 : 1;
    int zeros = 0;
    for (int j = 0; j < 64; j++) if (ei_raw[2 * j + 1] == 0) zeros++;
    *iflag = (zeros >= 60) ? 1 : 0;
    *errflag = 0;
  }
}

__global__ void k_convert(CvtParams P, const int* __restrict__ flag)
{
  const int pi  = blockIdx.y;
  const int idx = blockIdx.x * 256 + threadIdx.x;
  if (idx >= P.n[pi]) return;
  if (*flag == 0) P.dst[pi][idx] = ((const float*)P.src[pi])[idx];
  else            P.dst[pi][idx] = bf2f(((const u16*)P.src[pi])[idx]);
}

// ---------------- validators ----------------

__global__ void k_check_sorted(const int* __restrict__ batch, const int* __restrict__ iflag,
                               int n, int* __restrict__ errflag)
{
  int i = blockIdx.x * 256 + threadIdx.x;
  if (i < n - 1){
    if (geti(batch, i, *iflag) > geti(batch, i + 1, *iflag)) atomicOr(errflag, 8);
  }
}

__global__ void k_check_x(const int* __restrict__ x, const int* __restrict__ iflag,
                          int n, int V, int* __restrict__ errflag)
{
  int i = blockIdx.x * 256 + threadIdx.x;
  if (i < n){
    int v = geti(x, i, *iflag);
    if ((unsigned)v >= (unsigned)V) atomicOr(errflag, 16);
  }
}

__global__ void k_check_edges(const int* __restrict__ ei, const int* __restrict__ iflag,
                              int E, int n, int* __restrict__ errflag)
{
  int e = blockIdx.x * 256 + threadIdx.x;
  if (e < E){
    int enc = *iflag;
    int s = geti(ei, e, enc);
    int d = geti(ei, E + e, enc);
    if ((unsigned)s >= (unsigned)n || (unsigned)d >= (unsigned)n) atomicOr(errflag, 32);
  }
}

// ---------------- CSR build ----------------

__global__ void k_hist(const int* __restrict__ ei, const int* __restrict__ iflag,
                       int* __restrict__ counts, int E, int n)
{
  int e = blockIdx.x * 256 + threadIdx.x;
  if (e < E){
    int d = geti(ei, E + e, *iflag);
    d = min(max(d, 0), n - 1);
    atomicAdd(&counts[d], 1);
  }
}

__global__ void k_scanA(const int* __restrict__ counts, int* __restrict__ rowptr,
                        int* __restrict__ bsums, int n)
{
  __shared__ int sd[1024];
  int tid = threadIdx.x;
  int gid = blockIdx.x * 1024 + tid;
  int v = (gid < n) ? counts[gid] : 0;
  sd[tid] = v;
  __syncthreads();
  for (int off = 1; off < 1024; off <<= 1){
    int t = 0;
    if (tid >= off) t = sd[tid - off];
    __syncthreads();
    if (tid >= off) sd[tid] += t;
    __syncthreads();
  }
  if (gid < n) rowptr[gid] = sd[tid] - v;
  if (tid == 1023) bsums[blockIdx.x] = sd[1023];
}

__global__ void k_scanB(const int* __restrict__ bsums, int* __restrict__ boffs, int nb)
{
  __shared__ int sd[128];
  int tid = threadIdx.x;
  int v = (tid < nb) ? bsums[tid] : 0;
  sd[tid] = v;
  __syncthreads();
  for (int off = 1; off < 128; off <<= 1){
    int t = 0;
    if (tid >= off) t = sd[tid - off];
    __syncthreads();
    if (tid >= off) sd[tid] += t;
    __syncthreads();
  }
  if (tid < nb) boffs[tid] = sd[tid] - v;
}

__global__ void k_scanC(int* __restrict__ rowptr, const int* __restrict__ boffs,
                        int* __restrict__ cursor, int n, int Etot)
{
  int gid = blockIdx.x * 1024 + threadIdx.x;
  if (gid < n){
    int v = rowptr[gid] + boffs[blockIdx.x];
    rowptr[gid] = v;
    cursor[gid] = v;
  }
  if (gid == 0) rowptr[n] = Etot;
}

__global__ void k_scatter(const int* __restrict__ ei, const int* __restrict__ iflag,
                          int* __restrict__ cursor, int* __restrict__ csr, int E, int n)
{
  int e = blockIdx.x * 256 + threadIdx.x;
  if (e < E){
    int enc = *iflag;
    int s = geti(ei, e, enc);
    int d = geti(ei, E + e, enc);
    d = min(max(d, 0), n - 1);
    int pos = atomicAdd(&cursor[d], 1);
    csr[pos] = s;
  }
}

__global__ void k_check_rows(const int* __restrict__ rowptr, const int* __restrict__ cursor,
                             int n, int* __restrict__ errflag)
{
  int i = blockIdx.x * 256 + threadIdx.x;
  if (i < n){
    if (cursor[i] != rowptr[i + 1]) atomicOr(errflag, 1);
    if (i == 0 && rowptr[0] != 0)   atomicOr(errflag, 4);
  }
}

__global__ void k_check_csr(const int* __restrict__ csr, int E, int n, int* __restrict__ errflag)
{
  int e = blockIdx.x * 256 + threadIdx.x;
  if (e < E && (unsigned)csr[e] >= (unsigned)n) atomicOr(errflag, 2);
}

__global__ void k_stamp_if(const int* __restrict__ errflag, float* __restrict__ out, int nel)
{
  int f = *errflag;
  if (f == 0) return;
  float s = 500.0f + 100.0f * (float)f;
  int i = blockIdx.x * 256 + threadIdx.x;
  if (i < nel) out[i] = s;
}

__global__ void k_stamp(float* __restrict__ out, int nel, float val)
{
  int i = blockIdx.x * 256 + threadIdx.x;
  if (i < nel) out[i] = val;
}

// ---------------- layer-1 vocab table: LN + W1 + al per vocab id (51 rows) ----------------

__global__ void k_prep(const float* __restrict__ emb,
                       const float* __restrict__ ln_g, const float* __restrict__ ln_b,
                       const float* __restrict__ W1, const float* __restrict__ a_src,
                       const float* __restrict__ a_dst,
                       u16* __restrict__ xwv, float* __restrict__ alsv, float* __restrict__ aldv)
{
  __shared__ float se[32];
  __shared__ float stats[2];
  __shared__ float sxw[128];
  const int v = blockIdx.x, t = threadIdx.x;
  if (t < 32) se[t] = emb[v * 32 + t];
  __syncthreads();
  if (t == 0){
    float s1 = 0.f, s2 = 0.f;
    for (int k = 0; k < 32; k++){ s1 += se[k]; s2 += se[k] * se[k]; }
    float mu = s1 * (1.f / 32.f);
    float var = s2 * (1.f / 32.f) - mu * mu;
    stats[0] = mu; stats[1] = rsqrtf(var + LN_EPS);
  }
  __syncthreads();
  const float mu = stats[0], rs = stats[1];
  float o = 0.f;
  for (int k = 0; k < 32; k++){
    float xe = (se[k] - mu) * rs * ln_g[k] + ln_b[k];
    o += xe * W1[k * 128 + t];
  }
  sxw[t] = o;
  xwv[v * 128 + t] = f2bf(o);
  __syncthreads();
  if (t < 2){
    float ps = 0.f, pd = 0.f;
    for (int d = 0; d < 64; d++){
      float vv = sxw[t * 64 + d];
      ps += vv * a_src[t * 64 + d];
      pd += vv * a_dst[t * 64 + d];
    }
    alsv[2 * v + t] = ps;
    aldv[2 * v + t] = pd;
  }
}

// lookup: materialize per-node xw row + al pair from the 51-row tables
__global__ void k_lookup(const int* __restrict__ x, const int* __restrict__ iflag,
                         const u16* __restrict__ xwv, const float* __restrict__ alsv,
                         const float* __restrict__ aldv, int N, int V,
                         u16* __restrict__ xw, float* __restrict__ al_s, float* __restrict__ al_d)
{
  const int enc = *iflag;
  const int tid = threadIdx.x;
  const int c = tid & 15;
  for (int base = blockIdx.x * 16; base < N; base += gridDim.x * 16){
    int i = base + (tid >> 4);
    if (i < N){
      int v = geti(x, i, enc);
      v = min(max(v, 0), V - 1);
      uint4 row = *(const uint4*)(xwv + v * 128 + c * 8);
      *(uint4*)(xw + (size_t)i * 128 + c * 8) = row;
      if (c == 0){ float2 a = *(const float2*)(alsv + 2 * v); *(float2*)(al_s + 2 * i) = a; }
      if (c == 1){ float2 a = *(const float2*)(aldv + 2 * v); *(float2*)(al_d + 2 * i) = a; }
    }
  }
}

// ---------------- GAT: one wave per dst node, quad-edge vectorized gather ----------------

__global__ __launch_bounds__(64, 8) void k_gatw(
    const int* __restrict__ rowptr, const int* __restrict__ csr,
    const float* __restrict__ al_s, const float* __restrict__ al_d,
    const u16* __restrict__ xw, const float* __restrict__ bias,
    int apply_act, float* __restrict__ out)
{
  const int i    = blockIdx.x;
  const int lane = threadIdx.x;
  const int sub  = lane >> 4;          // which edge of the quad
  const int c16  = lane & 15;          // 16 lanes x 8 channels = 128
  const int r0 = rowptr[i], deg = rowptr[i + 1] - r0, total = deg + 1;
  const float ad0 = al_d[2 * i], ad1 = al_d[2 * i + 1];

  // phase A: per-head max over edges (strided, butterfly)
  float m0 = -3.0e38f, m1 = -3.0e38f;
  for (int k = lane; k < total; k += 64){
    int s = (k < deg) ? csr[r0 + k] : i;
    float a0 = lrelu(al_s[2 * s]     + ad0, NEG_GAT);
    float a1 = lrelu(al_s[2 * s + 1] + ad1, NEG_GAT);
    m0 = fmaxf(m0, a0); m1 = fmaxf(m1, a1);
  }
  #pragma unroll
  for (int off = 32; off; off >>= 1){
    m0 = fmaxf(m0, __shfl_xor(m0, off));
    m1 = fmaxf(m1, __shfl_xor(m1, off));
  }

  // phase B+C: exp/sum and unnormalized gather, chunk of 64 edges
  float sum0 = 0.f, sum1 = 0.f;
  float acc[8];
  #pragma unroll
  for (int r = 0; r < 8; r++) acc[r] = 0.f;

  for (int base = 0; base < total; base += 64){
    int k = base + lane;
    int s = i; float ex0 = 0.f, ex1 = 0.f;
    if (k < total){
      s = (k < deg) ? csr[r0 + k] : i;
      ex0 = __expf(lrelu(al_s[2 * s]     + ad0, NEG_GAT) - m0);
      ex1 = __expf(lrelu(al_s[2 * s + 1] + ad1, NEG_GAT) - m1);
    }
    sum0 += ex0; sum1 += ex1;

    int cnt  = min(64, total - base);
    int qmax = (cnt + 3) & ~3;
    for (int q = 0; q < qmax; q += 4){
      int   j  = q + sub;
      int   sj = __shfl(s, j);
      float e0 = __shfl(ex0, j);
      float e1 = __shfl(ex1, j);
      float ej = (c16 < 8) ? e0 : e1;     // lanes j>=cnt carry ex=0 -> contribute 0
      uint4 w = *(const uint4*)(xw + (size_t)sj * 128 + c16 * 8);
      acc[0] += ej * bf2f(w.x & 0xffffu); acc[1] += ej * bf2f(w.x >> 16);
      acc[2] += ej * bf2f(w.y & 0xffffu); acc[3] += ej * bf2f(w.y >> 16);
      acc[4] += ej * bf2f(w.z & 0xffffu); acc[5] += ej * bf2f(w.z >> 16);
      acc[6] += ej * bf2f(w.w & 0xffffu); acc[7] += ej * bf2f(w.w >> 16);
    }
  }
  #pragma unroll
  for (int off = 32; off; off >>= 1){
    sum0 += __shfl_xor(sum0, off);
    sum1 += __shfl_xor(sum1, off);
  }
  // reduce the 4 edge-subgroups
  #pragma unroll
  for (int r = 0; r < 8; r++){
    acc[r] += __shfl_xor(acc[r], 16);
    acc[r] += __shfl_xor(acc[r], 32);
  }

  if (sub == 0){
    float inv = 1.f / ((c16 < 8) ? sum0 : sum1);
    const float4* bp = (const float4*)(bias + c16 * 8);
    float4 b0 = bp[0], b1 = bp[1];
    float4 o0, o1;
    o0.x = acc[0] * inv + b0.x; o0.y = acc[1] * inv + b0.y;
    o0.z = acc[2] * inv + b0.z; o0.w = acc[3] * inv + b0.w;
    o1.x = acc[4] * inv + b1.x; o1.y = acc[5] * inv + b1.y;
    o1.z = acc[6] * inv + b1.z; o1.w = acc[7] * inv + b1.w;
    if (apply_act){
      o0.x = lrelu(o0.x, NEG_ACT); o0.y = lrelu(o0.y, NEG_ACT);
      o0.z = lrelu(o0.z, NEG_ACT); o0.w = lrelu(o0.w, NEG_ACT);
      o1.x = lrelu(o1.x, NEG_ACT); o1.y = lrelu(o1.y, NEG_ACT);
      o1.z = lrelu(o1.z, NEG_ACT); o1.w = lrelu(o1.w, NEG_ACT);
    }
    float* op = out + (size_t)i * 128 + c16 * 8;
    *(float4*)op       = o0;
    *(float4*)(op + 4) = o1;
  }
}

// ---------------- layer-2 node prep: weight-stationary GEMV (xw2 = h1 @ W2, al) ----------------

__global__ __launch_bounds__(128, 3) void k_node2w(
    const float* __restrict__ h1, const float* __restrict__ W2,
    const float* __restrict__ a_src, const float* __restrict__ a_dst,
    int N, int npb,
    u16* __restrict__ xw, float* __restrict__ al_s, float* __restrict__ al_d)
{
  const int t = threadIdx.x;
  float w[128];
  #pragma unroll
  for (int k = 0; k < 128; k++) w[k] = W2[k * 128 + t];
  const float as  = a_src[t];
  const float adw = a_dst[t];
  const int wave = t >> 6;

  int start = blockIdx.x * npb;
  int end   = min(start + npb, N);
  for (int i = start; i < end; i++){
    const float* hr = h1 + (size_t)i * 128;   // wave-uniform -> scalar loads
    float o = 0.f;
    #pragma unroll
    for (int k = 0; k < 128; k++) o += hr[k] * w[k];
    xw[(size_t)i * 128 + t] = f2bf(o);
    float ps = o * as, pd = o * adw;
    #pragma unroll
    for (int off = 32; off; off >>= 1){
      ps += __shfl_xor(ps, off);
      pd += __shfl_xor(pd, off);
    }
    if ((t & 63) == 0){
      al_s[2 * i + wave] = ps;
      al_d[2 * i + wave] = pd;
    }
  }
}

// ---------------- gate scalar: weight-stationary ----------------

__global__ __launch_bounds__(64, 3) void k_gatesw(
    const float* __restrict__ h, const float* __restrict__ gw1,
    const float* __restrict__ gb1, const float* __restrict__ gw2,
    const float* __restrict__ gb2, int N, int npb,
    float* __restrict__ gate)
{
  const int t = threadIdx.x;                 // hidden unit j = t (64)
  float w[128];
  #pragma unroll
  for (int k = 0; k < 128; k++) w[k] = gw1[k * 64 + t];
  const float bb  = gb1[t];
  const float g2  = gw2[t];
  const float g2b = gb2[0];

  int start = blockIdx.x * npb;
  int end   = min(start + npb, N);
  for (int i = start; i < end; i++){
    const float* hr = h + (size_t)i * 128;
    float o = 0.f;
    #pragma unroll
    for (int k = 0; k < 128; k++) o += hr[k] * w[k];
    o = lrelu(o + bb, NEG_ACT);
    float q = o * g2;
    #pragma unroll
    for (int off = 32; off; off >>= 1) q += __shfl_xor(q, off);
    if (t == 0) gate[i] = q + g2b;
  }
}

// ---------------- per-graph softmax pooling (parallel max/sum) ----------------

__global__ void k_graphsw(const int* __restrict__ batch, const int* __restrict__ iflag,
                          const float* __restrict__ gate,
                          const float* __restrict__ h, float* __restrict__ zout, int N)
{
  __shared__ int   range[2];
  __shared__ float red[4];
  const int g = blockIdx.x, t = threadIdx.x;
  const int wave = t >> 6;
  if (t == 0){
    const int enc = *iflag;
    int lo = 0, hi = N;
    while (lo < hi){ int mid = (lo + hi) >> 1; if (geti(batch, mid, enc) < g) lo = mid + 1; else hi = mid; }
    range[0] = lo;
    hi = N;
    while (lo < hi){ int mid = (lo + hi) >> 1; if (geti(batch, mid, enc) < g + 1) lo = mid + 1; else hi = mid; }
    range[1] = lo;
  }
  __syncthreads();
  const int st = range[0], en = range[1];

  float m = -3.0e38f;
  for (int k = st + t; k < en; k += 128) m = fmaxf(m, gate[k]);
  #pragma unroll
  for (int off = 32; off; off >>= 1) m = fmaxf(m, __shfl_xor(m, off));
  if ((t & 63) == 0) red[wave] = m;
  __syncthreads();
  m = fmaxf(red[0], red[1]);

  float s = 0.f;
  for (int k = st + t; k < en; k += 128) s += __expf(gate[k] - m);
  #pragma unroll
  for (int off = 32; off; off >>= 1) s += __shfl_xor(s, off);
  if ((t & 63) == 0) red[2 + wave] = s;
  __syncthreads();
  s = red[2] + red[3];

  float z = 0.f;
  const float inv = 1.f / s;
  for (int k = st; k < en; k++){
    float wk = __expf(gate[k] - m) * inv;     // gate[k] wave-uniform -> scalar load
    z += wk * h[(size_t)k * 128 + t];
  }
  zout[(size_t)g * 128 + t] = z;
}

// ---------------- launch ----------------

extern "C" void kernel_launch(void* const* d_in, const int* in_sizes, int n_in,
                              void* d_out, int out_size, void* d_ws, size_t ws_size,
                              hipStream_t stream)
{
  const int* x      = (const int*)d_in[0];
  const int* ei     = (const int*)d_in[1];
  const int* batch  = (const int*)d_in[2];

  const int N = in_sizes[0];
  const int E = in_sizes[1] / 2;
  const int V = in_sizes[3] / 32;
  const int G = out_size / 128 - N;

  char* p = (char*)d_ws;
  auto alloc = [&](size_t bytes) -> char* {
    char* r = p; p += (bytes + 255) & ~(size_t)255; return r;
  };
  int*   multi  = (int*)  alloc((size_t)N * 4);       // counts -> cursor -> gate
  int*   rowptr = (int*)  alloc((size_t)(N + 1) * 4);
  int*   csr    = (int*)  alloc((size_t)E * 4);
  int*   bsums  = (int*)  alloc(4096);
  int*   boffs  = (int*)  alloc(4096);
  int*   flags  = (int*)  alloc(256);
  int*   fflag  = flags;
  int*   iflag  = flags + 1;
  int*   errflg = flags + 2;
  float* al_s   = (float*)alloc((size_t)N * 2 * 4);
  float* al_d   = (float*)alloc((size_t)N * 2 * 4);
  u16*   xw     = (u16*)  alloc((size_t)N * 128 * 2);
  u16*   xwv    = (u16*)  alloc((size_t)V * 128 * 2);
  float* alsv   = (float*)alloc((size_t)V * 2 * 4);
  float* aldv   = (float*)alloc((size_t)V * 2 * 4);

  CvtParams cp;
  float* fpar[NPARAM];
  int maxn = 0;
  for (int pi = 0; pi < NPARAM; pi++){
    int n = in_sizes[3 + pi];
    fpar[pi] = (float*)alloc((size_t)n * 4);
    cp.src[pi] = d_in[3 + pi];
    cp.dst[pi] = fpar[pi];
    cp.n[pi]   = n;
    if (n > maxn) maxn = n;
  }
  const size_t needed = (size_t)(p - (char*)d_ws);

  const float* emb    = fpar[0];
  const float* ln_g   = fpar[1];
  const float* ln_b   = fpar[2];
  const float* W1     = fpar[3];
  const float* a_src1 = fpar[4];
  const float* a_dst1 = fpar[5];
  const float* b1     = fpar[6];
  const float* W2     = fpar[7];
  const float* a_src2 = fpar[8];
  const float* a_dst2 = fpar[9];
  const float* b2     = fpar[10];
  const float* gw1    = fpar[11];
  const float* gb1    = fpar[12];
  const float* gw2    = fpar[13];
  const float* gb2    = fpar[14];
  (void)n_in;

  int ob = (out_size + 255) / 256;
  if (ws_size < needed){
    k_stamp<<<ob, 256, 0, stream>>>((float*)d_out, out_size, 9999.0f);
    return;
  }

  int*   counts = multi;
  int*   cursor = multi;
  float* gate   = (float*)multi;
  float* hbuf   = (float*)d_out;
  float* zbuf   = (float*)d_out + (size_t)N * 128;

  k_detect<<<1, 64, 0, stream>>>((const u32*)d_in[4], ei, fflag, iflag, errflg);
  dim3 cgrid((maxn + 255) / 256, NPARAM);
  k_convert<<<cgrid, 256, 0, stream>>>(cp, fflag);

  int eb = (E + 255) / 256;
  int nb = (N + 1023) / 1024;
  int nb256 = (N + 255) / 256;

  k_check_sorted<<<nb256, 256, 0, stream>>>(batch, iflag, N, errflg);
  k_check_x<<<nb256, 256, 0, stream>>>(x, iflag, N, V, errflg);
  k_check_edges<<<eb, 256, 0, stream>>>(ei, iflag, E, N, errflg);

  hipMemsetAsync(counts, 0, (size_t)N * 4, stream);
  hipMemsetAsync(csr, 0xFF, (size_t)E * 4, stream);
  k_hist<<<eb, 256, 0, stream>>>(ei, iflag, counts, E, N);
  k_scanA<<<nb, 1024, 0, stream>>>(counts, rowptr, bsums, N);
  k_scanB<<<1, 128, 0, stream>>>(bsums, boffs, nb);
  k_scanC<<<nb, 1024, 0, stream>>>(rowptr, boffs, cursor, N, E);
  k_scatter<<<eb, 256, 0, stream>>>(ei, iflag, cursor, csr, E, N);
  k_check_rows<<<nb256, 256, 0, stream>>>(rowptr, cursor, N, errflg);
  k_check_csr<<<eb, 256, 0, stream>>>(csr, E, N, errflg);

  // layer 1 via vocab table
  k_prep<<<V, 128, 0, stream>>>(emb, ln_g, ln_b, W1, a_src1, a_dst1, xwv, alsv, aldv);
  k_lookup<<<1024, 256, 0, stream>>>(x, iflag, xwv, alsv, aldv, N, V, xw, al_s, al_d);

  k_gatw<<<N, 64, 0, stream>>>(rowptr, csr, al_s, al_d, xw, b1, 1, hbuf);

  const int blocks2 = 2048;
  const int npb = (N + blocks2 - 1) / blocks2;
  k_node2w<<<blocks2, 128, 0, stream>>>(hbuf, W2, a_src2, a_dst2, N, npb, xw, al_s, al_d);

  k_gatw<<<N, 64, 0, stream>>>(rowptr, csr, al_s, al_d, xw, b2, 0, hbuf);

  k_gatesw<<<blocks2, 64, 0, stream>>>(hbuf, gw1, gb1, gw2, gb2, N, npb, gate);
  k_graphsw<<<G, 128, 0, stream>>>(batch, iflag, gate, hbuf, zbuf, N);

  k_stamp_if<<<ob, 256, 0, stream>>>(errflg, (float*)d_out, out_size);
}

// Round 11
// 582.521 us; speedup vs baseline: 3.2456x; 1.5349x over previous
//
#include <hip/hip_runtime.h>
#include <hip/hip_bf16.h>
#include <stdint.h>

typedef unsigned short u16;
typedef unsigned int   u32;
typedef __attribute__((ext_vector_type(8))) short bf16x8;
typedef __attribute__((ext_vector_type(4))) float f32x4;

#define NEG_GAT 0.2f
#define NEG_ACT 0.05f
#define LN_EPS  1e-5f
#define NPARAM  15

__device__ __forceinline__ float bf2f(u32 bits16){
  union { u32 u; float f; } v; v.u = bits16 << 16; return v.f;
}
__device__ __forceinline__ u16 f2bf(float f){
  union { float f; u32 u; } v; v.f = f;
  u32 u = v.u;
  u32 r = (u + 0x7fffu + ((u >> 16) & 1u)) >> 16;
  return (u16)r;
}
__device__ __forceinline__ float lrelu(float x, float s){ return x > 0.f ? x : s * x; }

__device__ __forceinline__ int geti(const int* __restrict__ p, int i, int enc){
  return p[enc ? (2 * i) : i];
}

// ---------------- dtype detection ----------------

struct CvtParams {
  const void* src[NPARAM];
  float*      dst[NPARAM];
  int         n[NPARAM];
};

__global__ void k_detect(const u32* __restrict__ ln_g_raw, const int* __restrict__ ei_raw,
                         int* __restrict__ fflag, int* __restrict__ iflag,
                         int* __restrict__ errflag)
{
  if (threadIdx.x == 0){
    *fflag = (ln_g_raw[0] == 0x3F800000u) ? 0 : 1;
    int zeros = 0;
    for (int j = 0; j < 64; j++) if (ei_raw[2 * j + 1] == 0) zeros++;
    *iflag = (zeros >= 60) ? 1 : 0;
    *errflag = 0;
  }
}

__global__ void k_convert(CvtParams P, const int* __restrict__ flag)
{
  const int pi  = blockIdx.y;
  const int idx = blockIdx.x * 256 + threadIdx.x;
  if (idx >= P.n[pi]) return;
  if (*flag == 0) P.dst[pi][idx] = ((const float*)P.src[pi])[idx];
  else            P.dst[pi][idx] = bf2f(((const u16*)P.src[pi])[idx]);
}

// ---------------- validators ----------------

__global__ void k_check_sorted(const int* __restrict__ batch, const int* __restrict__ iflag,
                               int n, int* __restrict__ errflag)
{
  int i = blockIdx.x * 256 + threadIdx.x;
  if (i < n - 1){
    if (geti(batch, i, *iflag) > geti(batch, i + 1, *iflag)) atomicOr(errflag, 8);
  }
}

__global__ void k_check_x(const int* __restrict__ x, const int* __restrict__ iflag,
                          int n, int V, int* __restrict__ errflag)
{
  int i = blockIdx.x * 256 + threadIdx.x;
  if (i < n){
    int v = geti(x, i, *iflag);
    if ((unsigned)v >= (unsigned)V) atomicOr(errflag, 16);
  }
}

__global__ void k_check_edges(const int* __restrict__ ei, const int* __restrict__ iflag,
                              int E, int n, int* __restrict__ errflag)
{
  int e = blockIdx.x * 256 + threadIdx.x;
  if (e < E){
    int enc = *iflag;
    int s = geti(ei, e, enc);
    int d = geti(ei, E + e, enc);
    if ((unsigned)s >= (unsigned)n || (unsigned)d >= (unsigned)n) atomicOr(errflag, 32);
  }
}

// ---------------- CSR build ----------------

__global__ void k_hist(const int* __restrict__ ei, const int* __restrict__ iflag,
                       int* __restrict__ counts, int E, int n)
{
  int e = blockIdx.x * 256 + threadIdx.x;
  if (e < E){
    int d = geti(ei, E + e, *iflag);
    d = min(max(d, 0), n - 1);
    atomicAdd(&counts[d], 1);
  }
}

__global__ void k_scanA(const int* __restrict__ counts, int* __restrict__ rowptr,
                        int* __restrict__ bsums, int n)
{
  __shared__ int sd[1024];
  int tid = threadIdx.x;
  int gid = blockIdx.x * 1024 + tid;
  int v = (gid < n) ? counts[gid] : 0;
  sd[tid] = v;
  __syncthreads();
  for (int off = 1; off < 1024; off <<= 1){
    int t = 0;
    if (tid >= off) t = sd[tid - off];
    __syncthreads();
    if (tid >= off) sd[tid] += t;
    __syncthreads();
  }
  if (gid < n) rowptr[gid] = sd[tid] - v;
  if (tid == 1023) bsums[blockIdx.x] = sd[1023];
}

__global__ void k_scanB(const int* __restrict__ bsums, int* __restrict__ boffs, int nb)
{
  __shared__ int sd[128];
  int tid = threadIdx.x;
  int v = (tid < nb) ? bsums[tid] : 0;
  sd[tid] = v;
  __syncthreads();
  for (int off = 1; off < 128; off <<= 1){
    int t = 0;
    if (tid >= off) t = sd[tid - off];
    __syncthreads();
    if (tid >= off) sd[tid] += t;
    __syncthreads();
  }
  if (tid < nb) boffs[tid] = sd[tid] - v;
}

__global__ void k_scanC(int* __restrict__ rowptr, const int* __restrict__ boffs,
                        int* __restrict__ cursor, int n, int Etot)
{
  int gid = blockIdx.x * 1024 + threadIdx.x;
  if (gid < n){
    int v = rowptr[gid] + boffs[blockIdx.x];
    rowptr[gid] = v;
    cursor[gid] = v;
  }
  if (gid == 0) rowptr[n] = Etot;
}

__global__ void k_scatter(const int* __restrict__ ei, const int* __restrict__ iflag,
                          int* __restrict__ cursor, int* __restrict__ csr, int E, int n)
{
  int e = blockIdx.x * 256 + threadIdx.x;
  if (e < E){
    int enc = *iflag;
    int s = geti(ei, e, enc);
    int d = geti(ei, E + e, enc);
    d = min(max(d, 0), n - 1);
    int pos = atomicAdd(&cursor[d], 1);
    csr[pos] = s;
  }
}

__global__ void k_check_rows(const int* __restrict__ rowptr, const int* __restrict__ cursor,
                             int n, int* __restrict__ errflag)
{
  int i = blockIdx.x * 256 + threadIdx.x;
  if (i < n){
    if (cursor[i] != rowptr[i + 1]) atomicOr(errflag, 1);
    if (i == 0 && rowptr[0] != 0)   atomicOr(errflag, 4);
  }
}

__global__ void k_check_csr(const int* __restrict__ csr, int E, int n, int* __restrict__ errflag)
{
  int e = blockIdx.x * 256 + threadIdx.x;
  if (e < E && (unsigned)csr[e] >= (unsigned)n) atomicOr(errflag, 2);
}

__global__ void k_stamp_if(const int* __restrict__ errflag, float* __restrict__ out, int nel)
{
  int f = *errflag;
  if (f == 0) return;
  float s = 500.0f + 100.0f * (float)f;
  int i = blockIdx.x * 256 + threadIdx.x;
  if (i < nel) out[i] = s;
}

__global__ void k_stamp(float* __restrict__ out, int nel, float val)
{
  int i = blockIdx.x * 256 + threadIdx.x;
  if (i < nel) out[i] = val;
}

// ---------------- layer-1 vocab table ----------------

__global__ void k_prep(const float* __restrict__ emb,
                       const float* __restrict__ ln_g, const float* __restrict__ ln_b,
                       const float* __restrict__ W1, const float* __restrict__ a_src,
                       const float* __restrict__ a_dst,
                       u16* __restrict__ xwv, float* __restrict__ alsv, float* __restrict__ aldv)
{
  __shared__ float se[32];
  __shared__ float stats[2];
  __shared__ float sxw[128];
  const int v = blockIdx.x, t = threadIdx.x;
  if (t < 32) se[t] = emb[v * 32 + t];
  __syncthreads();
  if (t == 0){
    float s1 = 0.f, s2 = 0.f;
    for (int k = 0; k < 32; k++){ s1 += se[k]; s2 += se[k] * se[k]; }
    float mu = s1 * (1.f / 32.f);
    float var = s2 * (1.f / 32.f) - mu * mu;
    stats[0] = mu; stats[1] = rsqrtf(var + LN_EPS);
  }
  __syncthreads();
  const float mu = stats[0], rs = stats[1];
  float o = 0.f;
  for (int k = 0; k < 32; k++){
    float xe = (se[k] - mu) * rs * ln_g[k] + ln_b[k];
    o += xe * W1[k * 128 + t];
  }
  sxw[t] = o;
  xwv[v * 128 + t] = f2bf(o);
  __syncthreads();
  if (t < 2){
    float ps = 0.f, pd = 0.f;
    for (int d = 0; d < 64; d++){
      float vv = sxw[t * 64 + d];
      ps += vv * a_src[t * 64 + d];
      pd += vv * a_dst[t * 64 + d];
    }
    alsv[2 * v + t] = ps;
    aldv[2 * v + t] = pd;
  }
}

__global__ void k_lookup(const int* __restrict__ x, const int* __restrict__ iflag,
                         const u16* __restrict__ xwv, const float* __restrict__ alsv,
                         const float* __restrict__ aldv, int N, int V,
                         u16* __restrict__ xw, float* __restrict__ al_s, float* __restrict__ al_d)
{
  const int enc = *iflag;
  const int tid = threadIdx.x;
  const int c = tid & 15;
  for (int base = blockIdx.x * 16; base < N; base += gridDim.x * 16){
    int i = base + (tid >> 4);
    if (i < N){
      int v = geti(x, i, enc);
      v = min(max(v, 0), V - 1);
      uint4 row = *(const uint4*)(xwv + v * 128 + c * 8);
      *(uint4*)(xw + (size_t)i * 128 + c * 8) = row;
      if (c == 0){ float2 a = *(const float2*)(alsv + 2 * v); *(float2*)(al_s + 2 * i) = a; }
      if (c == 1){ float2 a = *(const float2*)(aldv + 2 * v); *(float2*)(al_d + 2 * i) = a; }
    }
  }
}

// ---------------- GAT: one wave per dst node ----------------

__global__ __launch_bounds__(64, 8) void k_gatw(
    const int* __restrict__ rowptr, const int* __restrict__ csr,
    const float* __restrict__ al_s, const float* __restrict__ al_d,
    const u16* __restrict__ xw, const float* __restrict__ bias,
    int apply_act, float* __restrict__ out)
{
  const int i    = blockIdx.x;
  const int lane = threadIdx.x;
  const int sub  = lane >> 4;
  const int c16  = lane & 15;
  const int r0 = rowptr[i], deg = rowptr[i + 1] - r0, total = deg + 1;
  const float ad0 = al_d[2 * i], ad1 = al_d[2 * i + 1];

  float m0 = -3.0e38f, m1 = -3.0e38f;
  for (int k = lane; k < total; k += 64){
    int s = (k < deg) ? csr[r0 + k] : i;
    float a0 = lrelu(al_s[2 * s]     + ad0, NEG_GAT);
    float a1 = lrelu(al_s[2 * s + 1] + ad1, NEG_GAT);
    m0 = fmaxf(m0, a0); m1 = fmaxf(m1, a1);
  }
  #pragma unroll
  for (int off = 32; off; off >>= 1){
    m0 = fmaxf(m0, __shfl_xor(m0, off));
    m1 = fmaxf(m1, __shfl_xor(m1, off));
  }

  float sum0 = 0.f, sum1 = 0.f;
  float acc[8];
  #pragma unroll
  for (int r = 0; r < 8; r++) acc[r] = 0.f;

  for (int base = 0; base < total; base += 64){
    int k = base + lane;
    int s = i; float ex0 = 0.f, ex1 = 0.f;
    if (k < total){
      s = (k < deg) ? csr[r0 + k] : i;
      ex0 = __expf(lrelu(al_s[2 * s]     + ad0, NEG_GAT) - m0);
      ex1 = __expf(lrelu(al_s[2 * s + 1] + ad1, NEG_GAT) - m1);
    }
    sum0 += ex0; sum1 += ex1;

    int cnt  = min(64, total - base);
    int qmax = (cnt + 3) & ~3;
    for (int q = 0; q < qmax; q += 4){
      int   j  = q + sub;
      int   sj = __shfl(s, j);
      float e0 = __shfl(ex0, j);
      float e1 = __shfl(ex1, j);
      float ej = (c16 < 8) ? e0 : e1;
      uint4 w = *(const uint4*)(xw + (size_t)sj * 128 + c16 * 8);
      acc[0] += ej * bf2f(w.x & 0xffffu); acc[1] += ej * bf2f(w.x >> 16);
      acc[2] += ej * bf2f(w.y & 0xffffu); acc[3] += ej * bf2f(w.y >> 16);
      acc[4] += ej * bf2f(w.z & 0xffffu); acc[5] += ej * bf2f(w.z >> 16);
      acc[6] += ej * bf2f(w.w & 0xffffu); acc[7] += ej * bf2f(w.w >> 16);
    }
  }
  #pragma unroll
  for (int off = 32; off; off >>= 1){
    sum0 += __shfl_xor(sum0, off);
    sum1 += __shfl_xor(sum1, off);
  }
  #pragma unroll
  for (int r = 0; r < 8; r++){
    acc[r] += __shfl_xor(acc[r], 16);
    acc[r] += __shfl_xor(acc[r], 32);
  }

  if (sub == 0){
    float inv = 1.f / ((c16 < 8) ? sum0 : sum1);
    const float4* bp = (const float4*)(bias + c16 * 8);
    float4 b0 = bp[0], b1 = bp[1];
    float4 o0, o1;
    o0.x = acc[0] * inv + b0.x; o0.y = acc[1] * inv + b0.y;
    o0.z = acc[2] * inv + b0.z; o0.w = acc[3] * inv + b0.w;
    o1.x = acc[4] * inv + b1.x; o1.y = acc[5] * inv + b1.y;
    o1.z = acc[6] * inv + b1.z; o1.w = acc[7] * inv + b1.w;
    if (apply_act){
      o0.x = lrelu(o0.x, NEG_ACT); o0.y = lrelu(o0.y, NEG_ACT);
      o0.z = lrelu(o0.z, NEG_ACT); o0.w = lrelu(o0.w, NEG_ACT);
      o1.x = lrelu(o1.x, NEG_ACT); o1.y = lrelu(o1.y, NEG_ACT);
      o1.z = lrelu(o1.z, NEG_ACT); o1.w = lrelu(o1.w, NEG_ACT);
    }
    float* op = out + (size_t)i * 128 + c16 * 8;
    *(float4*)op       = o0;
    *(float4*)(op + 4) = o1;
  }
}

// ---------------- pack weight matrix into MFMA B-fragment order ----------------
// B[k][n] (row-major k x ncols) -> pb[(ktile*ntiles+ntile)*64 + lane][8] bf16,
// fragment: lane holds B[k = ktile*32 + (lane>>4)*8 + j][n = ntile*16 + (lane&15)]

__global__ void k_packW(const float* __restrict__ W, int ncols, int ntiles,
                        u16* __restrict__ pb)
{
  const int ktile = blockIdx.x / ntiles;
  const int ntile = blockIdx.x % ntiles;
  const int lane  = threadIdx.x;
  const int n  = ntile * 16 + (lane & 15);
  const int k0 = ktile * 32 + (lane >> 4) * 8;
  u16* dst = pb + ((size_t)blockIdx.x * 64 + lane) * 8;
  #pragma unroll
  for (int j = 0; j < 8; j++)
    dst[j] = f2bf(W[(k0 + j) * ncols + n]);
}

// ---------------- layer-2 node prep: MFMA GEMM xw2 = h1 @ W2 (+ al epilogue) ----------------
// grid: ceil(N/64) blocks x 256 threads (4 waves x 16 rows)

__global__ __launch_bounds__(256, 2) void k_node2m(
    const float* __restrict__ h1, const u16* __restrict__ pb2,
    const float* __restrict__ a_src, const float* __restrict__ a_dst,
    int N, u16* __restrict__ xw, float* __restrict__ al_s, float* __restrict__ al_d)
{
  const int wave = threadIdx.x >> 6;
  const int lane = threadIdx.x & 63;
  const int rowbase = blockIdx.x * 64 + wave * 16;
  const int m    = lane & 15;
  const int quad = lane >> 4;

  int arow = rowbase + m; if (arow >= N) arow = N - 1;
  const float* aptr = h1 + (size_t)arow * 128 + quad * 8;

  f32x4 acc[8];
  #pragma unroll
  for (int nt = 0; nt < 8; nt++) acc[nt] = (f32x4){0.f, 0.f, 0.f, 0.f};

  #pragma unroll
  for (int kt = 0; kt < 4; kt++){
    float4 a0 = *(const float4*)(aptr + kt * 32);
    float4 a1 = *(const float4*)(aptr + kt * 32 + 4);
    bf16x8 af;
    af[0] = (short)f2bf(a0.x); af[1] = (short)f2bf(a0.y);
    af[2] = (short)f2bf(a0.z); af[3] = (short)f2bf(a0.w);
    af[4] = (short)f2bf(a1.x); af[5] = (short)f2bf(a1.y);
    af[6] = (short)f2bf(a1.z); af[7] = (short)f2bf(a1.w);
    const u16* bbase = pb2 + (((size_t)kt * 8) * 64 + lane) * 8;
    #pragma unroll
    for (int nt = 0; nt < 8; nt++){
      bf16x8 bf = *(const bf16x8*)(bbase + (size_t)nt * 64 * 8);
      acc[nt] = __builtin_amdgcn_mfma_f32_16x16x32_bf16(af, bf, acc[nt], 0, 0, 0);
    }
  }

  // epilogue: C layout col = nt*16+m, row = rowbase + quad*4 + r
  float asv[8], adv[8];
  #pragma unroll
  for (int nt = 0; nt < 8; nt++){
    asv[nt] = a_src[nt * 16 + m];
    adv[nt] = a_dst[nt * 16 + m];
  }
  #pragma unroll
  for (int r = 0; r < 4; r++){
    int row = rowbase + quad * 4 + r;
    bool ok = row < N;
    float s0 = 0.f, s1 = 0.f, d0 = 0.f, d1 = 0.f;
    #pragma unroll
    for (int nt = 0; nt < 8; nt++){
      float v = acc[nt][r];
      if (ok) xw[(size_t)row * 128 + nt * 16 + m] = f2bf(v);
      if (nt < 4){ s0 += v * asv[nt]; d0 += v * adv[nt]; }
      else       { s1 += v * asv[nt]; d1 += v * adv[nt]; }
    }
    #pragma unroll
    for (int off = 1; off < 16; off <<= 1){
      s0 += __shfl_xor(s0, off); s1 += __shfl_xor(s1, off);
      d0 += __shfl_xor(d0, off); d1 += __shfl_xor(d1, off);
    }
    if (ok && m == 0){
      al_s[2 * row] = s0; al_s[2 * row + 1] = s1;
      al_d[2 * row] = d0; al_d[2 * row + 1] = d1;
    }
  }
}

// ---------------- gate: MFMA GEMM t = h @ gw1, fused lrelu + dot(gw2) ----------------

__global__ __launch_bounds__(256, 2) void k_gatem(
    const float* __restrict__ h, const u16* __restrict__ pbg,
    const float* __restrict__ gb1, const float* __restrict__ gw2,
    const float* __restrict__ gb2, int N, float* __restrict__ gate)
{
  const int wave = threadIdx.x >> 6;
  const int lane = threadIdx.x & 63;
  const int rowbase = blockIdx.x * 64 + wave * 16;
  const int m    = lane & 15;
  const int quad = lane >> 4;

  int arow = rowbase + m; if (arow >= N) arow = N - 1;
  const float* aptr = h + (size_t)arow * 128 + quad * 8;

  f32x4 acc[4];
  #pragma unroll
  for (int nt = 0; nt < 4; nt++) acc[nt] = (f32x4){0.f, 0.f, 0.f, 0.f};

  #pragma unroll
  for (int kt = 0; kt < 4; kt++){
    float4 a0 = *(const float4*)(aptr + kt * 32);
    float4 a1 = *(const float4*)(aptr + kt * 32 + 4);
    bf16x8 af;
    af[0] = (short)f2bf(a0.x); af[1] = (short)f2bf(a0.y);
    af[2] = (short)f2bf(a0.z); af[3] = (short)f2bf(a0.w);
    af[4] = (short)f2bf(a1.x); af[5] = (short)f2bf(a1.y);
    af[6] = (short)f2bf(a1.z); af[7] = (short)f2bf(a1.w);
    const u16* bbase = pbg + (((size_t)kt * 4) * 64 + lane) * 8;
    #pragma unroll
    for (int nt = 0; nt < 4; nt++){
      bf16x8 bf = *(const bf16x8*)(bbase + (size_t)nt * 64 * 8);
      acc[nt] = __builtin_amdgcn_mfma_f32_16x16x32_bf16(af, bf, acc[nt], 0, 0, 0);
    }
  }

  float gbv[4], g2v[4];
  #pragma unroll
  for (int nt = 0; nt < 4; nt++){
    gbv[nt] = gb1[nt * 16 + m];
    g2v[nt] = gw2[nt * 16 + m];
  }
  const float g2b = gb2[0];
  #pragma unroll
  for (int r = 0; r < 4; r++){
    int row = rowbase + quad * 4 + r;
    float q = 0.f;
    #pragma unroll
    for (int nt = 0; nt < 4; nt++)
      q += lrelu(acc[nt][r] + gbv[nt], NEG_ACT) * g2v[nt];
    #pragma unroll
    for (int off = 1; off < 16; off <<= 1) q += __shfl_xor(q, off);
    if (row < N && m == 0) gate[row] = q + g2b;
  }
}

// ---------------- per-graph softmax pooling ----------------

__global__ void k_graphsw(const int* __restrict__ batch, const int* __restrict__ iflag,
                          const float* __restrict__ gate,
                          const float* __restrict__ h, float* __restrict__ zout, int N)
{
  __shared__ int   range[2];
  __shared__ float red[4];
  const int g = blockIdx.x, t = threadIdx.x;
  const int wave = t >> 6;
  if (t == 0){
    const int enc = *iflag;
    int lo = 0, hi = N;
    while (lo < hi){ int mid = (lo + hi) >> 1; if (geti(batch, mid, enc) < g) lo = mid + 1; else hi = mid; }
    range[0] = lo;
    hi = N;
    while (lo < hi){ int mid = (lo + hi) >> 1; if (geti(batch, mid, enc) < g + 1) lo = mid + 1; else hi = mid; }
    range[1] = lo;
  }
  __syncthreads();
  const int st = range[0], en = range[1];

  float m = -3.0e38f;
  for (int k = st + t; k < en; k += 128) m = fmaxf(m, gate[k]);
  #pragma unroll
  for (int off = 32; off; off >>= 1) m = fmaxf(m, __shfl_xor(m, off));
  if ((t & 63) == 0) red[wave] = m;
  __syncthreads();
  m = fmaxf(red[0], red[1]);

  float s = 0.f;
  for (int k = st + t; k < en; k += 128) s += __expf(gate[k] - m);
  #pragma unroll
  for (int off = 32; off; off >>= 1) s += __shfl_xor(s, off);
  if ((t & 63) == 0) red[2 + wave] = s;
  __syncthreads();
  s = red[2] + red[3];

  float z = 0.f;
  const float inv = 1.f / s;
  for (int k = st; k < en; k++){
    float wk = __expf(gate[k] - m) * inv;
    z += wk * h[(size_t)k * 128 + t];
  }
  zout[(size_t)g * 128 + t] = z;
}

// ---------------- launch ----------------

extern "C" void kernel_launch(void* const* d_in, const int* in_sizes, int n_in,
                              void* d_out, int out_size, void* d_ws, size_t ws_size,
                              hipStream_t stream)
{
  const int* x      = (const int*)d_in[0];
  const int* ei     = (const int*)d_in[1];
  const int* batch  = (const int*)d_in[2];

  const int N = in_sizes[0];
  const int E = in_sizes[1] / 2;
  const int V = in_sizes[3] / 32;
  const int G = out_size / 128 - N;

  char* p = (char*)d_ws;
  auto alloc = [&](size_t bytes) -> char* {
    char* r = p; p += (bytes + 255) & ~(size_t)255; return r;
  };
  int*   multi  = (int*)  alloc((size_t)N * 4);       // counts -> cursor -> gate
  int*   rowptr = (int*)  alloc((size_t)(N + 1) * 4);
  int*   csr    = (int*)  alloc((size_t)E * 4);
  int*   bsums  = (int*)  alloc(4096);
  int*   boffs  = (int*)  alloc(4096);
  int*   flags  = (int*)  alloc(256);
  int*   fflag  = flags;
  int*   iflag  = flags + 1;
  int*   errflg = flags + 2;
  float* al_s   = (float*)alloc((size_t)N * 2 * 4);
  float* al_d   = (float*)alloc((size_t)N * 2 * 4);
  u16*   xw     = (u16*)  alloc((size_t)N * 128 * 2);
  u16*   xwv    = (u16*)  alloc((size_t)V * 128 * 2);
  float* alsv   = (float*)alloc((size_t)V * 2 * 4);
  float* aldv   = (float*)alloc((size_t)V * 2 * 4);
  u16*   pb2    = (u16*)  alloc((size_t)128 * 128 * 2);  // W2 packed
  u16*   pbg    = (u16*)  alloc((size_t)128 * 64 * 2);   // gw1 packed

  CvtParams cp;
  float* fpar[NPARAM];
  int maxn = 0;
  for (int pi = 0; pi < NPARAM; pi++){
    int n = in_sizes[3 + pi];
    fpar[pi] = (float*)alloc((size_t)n * 4);
    cp.src[pi] = d_in[3 + pi];
    cp.dst[pi] = fpar[pi];
    cp.n[pi]   = n;
    if (n > maxn) maxn = n;
  }
  const size_t needed = (size_t)(p - (char*)d_ws);

  const float* emb    = fpar[0];
  const float* ln_g   = fpar[1];
  const float* ln_b   = fpar[2];
  const float* W1     = fpar[3];
  const float* a_src1 = fpar[4];
  const float* a_dst1 = fpar[5];
  const float* b1     = fpar[6];
  const float* W2     = fpar[7];
  const float* a_src2 = fpar[8];
  const float* a_dst2 = fpar[9];
  const float* b2     = fpar[10];
  const float* gw1    = fpar[11];
  const float* gb1    = fpar[12];
  const float* gw2    = fpar[13];
  const float* gb2    = fpar[14];
  (void)n_in;

  int ob = (out_size + 255) / 256;
  if (ws_size < needed){
    k_stamp<<<ob, 256, 0, stream>>>((float*)d_out, out_size, 9999.0f);
    return;
  }

  int*   counts = multi;
  int*   cursor = multi;
  float* gate   = (float*)multi;
  float* hbuf   = (float*)d_out;
  float* zbuf   = (float*)d_out + (size_t)N * 128;

  k_detect<<<1, 64, 0, stream>>>((const u32*)d_in[4], ei, fflag, iflag, errflg);
  dim3 cgrid((maxn + 255) / 256, NPARAM);
  k_convert<<<cgrid, 256, 0, stream>>>(cp, fflag);

  int eb = (E + 255) / 256;
  int nb = (N + 1023) / 1024;
  int nb256 = (N + 255) / 256;

  k_check_sorted<<<nb256, 256, 0, stream>>>(batch, iflag, N, errflg);
  k_check_x<<<nb256, 256, 0, stream>>>(x, iflag, N, V, errflg);
  k_check_edges<<<eb, 256, 0, stream>>>(ei, iflag, E, N, errflg);

  hipMemsetAsync(counts, 0, (size_t)N * 4, stream);
  hipMemsetAsync(csr, 0xFF, (size_t)E * 4, stream);
  k_hist<<<eb, 256, 0, stream>>>(ei, iflag, counts, E, N);
  k_scanA<<<nb, 1024, 0, stream>>>(counts, rowptr, bsums, N);
  k_scanB<<<1, 128, 0, stream>>>(bsums, boffs, nb);
  k_scanC<<<nb, 1024, 0, stream>>>(rowptr, boffs, cursor, N, E);
  k_scatter<<<eb, 256, 0, stream>>>(ei, iflag, cursor, csr, E, N);
  k_check_rows<<<nb256, 256, 0, stream>>>(rowptr, cursor, N, errflg);
  k_check_csr<<<eb, 256, 0, stream>>>(csr, E, N, errflg);

  // pack weights for MFMA
  k_packW<<<32, 64, 0, stream>>>(W2, 128, 8, pb2);
  k_packW<<<16, 64, 0, stream>>>(gw1, 64, 4, pbg);

  // layer 1 via vocab table
  k_prep<<<V, 128, 0, stream>>>(emb, ln_g, ln_b, W1, a_src1, a_dst1, xwv, alsv, aldv);
  k_lookup<<<1024, 256, 0, stream>>>(x, iflag, xwv, alsv, aldv, N, V, xw, al_s, al_d);

  k_gatw<<<N, 64, 0, stream>>>(rowptr, csr, al_s, al_d, xw, b1, 1, hbuf);

  const int gblk = (N + 63) / 64;
  k_node2m<<<gblk, 256, 0, stream>>>(hbuf, pb2, a_src2, a_dst2, N, xw, al_s, al_d);

  k_gatw<<<N, 64, 0, stream>>>(rowptr, csr, al_s, al_d, xw, b2, 0, hbuf);

  k_gatem<<<gblk, 256, 0, stream>>>(hbuf, pbg, gb1, gw2, gb2, N, gate);
  k_graphsw<<<G, 128, 0, stream>>>(batch, iflag, gate, hbuf, zbuf, N);

  k_stamp_if<<<ob, 256, 0, stream>>>(errflg, (float*)d_out, out_size);
}